// Round 1
// baseline (3559.910 us; speedup 1.0000x reference)
//
#include <hip/hip_runtime.h>
#include <hip/hip_bf16.h>
#include <cmath>

using bf16 = __hip_bfloat16;
typedef short bf16x8 __attribute__((ext_vector_type(8)));
typedef float f32x4 __attribute__((ext_vector_type(4)));

#define GLD_LDS16(g, l) __builtin_amdgcn_global_load_lds( \
    (const __attribute__((address_space(1))) void*)(g),   \
    (__attribute__((address_space(3))) void*)(l), 16, 0, 0)

#define MFMA16(a,b,c) __builtin_amdgcn_mfma_f32_16x16x32_bf16((a),(b),(c),0,0,0)

// problem constants
#define C_SP 800
#define C_SS 48
#define C_B  8
#define C_N  848      // SP+SS
#define C_NP 864      // padded to 27*32
#define C_DP 2048
#define C_DS 1024
#define C_H  8
#define C_HD 256
#define C_FP 16384
#define C_FS 4096

__device__ inline float wredsum(float v){
  #pragma unroll
  for (int o = 32; o > 0; o >>= 1) v += __shfl_down(v, o, 64);
  return v;
}
__device__ inline float wredmax(float v){
  #pragma unroll
  for (int o = 32; o > 0; o >>= 1) v = fmaxf(v, __shfl_down(v, o, 64));
  return v;
}

// ---------------- fp32 -> bf16 convert ----------------
__global__ void f2b_k(const float* __restrict__ s, bf16* __restrict__ d, long n){
  long i = ((long)blockIdx.x * 256 + threadIdx.x) * 4;
  if (i >= n) return;
  float4 v = *(const float4*)(s + i);
  d[i+0] = __float2bfloat16(v.x);
  d[i+1] = __float2bfloat16(v.y);
  d[i+2] = __float2bfloat16(v.z);
  d[i+3] = __float2bfloat16(v.w);
}

// ---------------- gemma RMS norm (D=2048) -> bf16 ----------------
__global__ void gemma_norm_k(const float* __restrict__ x, const float* __restrict__ w,
                             bf16* __restrict__ out){
  int row = blockIdx.x;
  int tid = threadIdx.x;
  const float* xr = x + (long)row * C_DP;
  float4 v0 = *(const float4*)(xr + tid*4);
  float4 v1 = *(const float4*)(xr + 1024 + tid*4);
  float ss = v0.x*v0.x + v0.y*v0.y + v0.z*v0.z + v0.w*v0.w
           + v1.x*v1.x + v1.y*v1.y + v1.z*v1.z + v1.w*v1.w;
  ss = wredsum(ss);
  __shared__ float red[4];
  if ((tid & 63) == 0) red[tid >> 6] = ss;
  __syncthreads();
  float tot = red[0] + red[1] + red[2] + red[3];
  float rs = rsqrtf(tot * (1.0f/2048.0f) + 1e-6f);
  bf16* orow = out + (long)row * C_DP;
  const float* wv = w;
  #pragma unroll
  for (int j = 0; j < 4; ++j){
    int c0 = tid*4 + j;
    orow[c0]        = __float2bfloat16(((&v0.x)[j]) * rs * (1.0f + wv[c0]));
    orow[c0 + 1024] = __float2bfloat16(((&v1.x)[j]) * rs * (1.0f + wv[c0 + 1024]));
  }
}

// ---------------- ada modulation: mod = cond @ w^T + b (both layers) ----------------
__global__ void ada_mod_k(const float* __restrict__ cond,
                          const float* __restrict__ w1, const float* __restrict__ b1,
                          const float* __restrict__ w2, const float* __restrict__ b2,
                          float* __restrict__ mod1, float* __restrict__ mod2){
  int idx = blockIdx.x * 256 + threadIdx.x;   // 2*3072 outputs
  int sel = idx / 3072, col = idx - sel * 3072;
  const float* w = (sel ? w2 : w1) + (long)col * C_DS;
  float acc[8] = {0,0,0,0,0,0,0,0};
  for (int k = 0; k < C_DS; k += 4){
    float4 wv = *(const float4*)(w + k);
    #pragma unroll
    for (int b = 0; b < 8; ++b){
      float4 cv = *(const float4*)(cond + b*C_DS + k);
      acc[b] += wv.x*cv.x + wv.y*cv.y + wv.z*cv.z + wv.w*cv.w;
    }
  }
  float bias = (sel ? b2 : b1)[col];
  float* m = sel ? mod2 : mod1;
  #pragma unroll
  for (int b = 0; b < 8; ++b) m[b*3072 + col] = acc[b] + bias;
}

// ---------------- ada norm (D=1024): rms(x)*(1+scale)+shift -> bf16 ----------------
__global__ void ada_norm_k(const float* __restrict__ x, const float* __restrict__ mod,
                           bf16* __restrict__ out){
  int row = blockIdx.x;       // 0..383
  int b = row / C_SS;
  int tid = threadIdx.x;
  const float* xr = x + (long)row * C_DS;
  float4 v = *(const float4*)(xr + tid*4);
  float ss = v.x*v.x + v.y*v.y + v.z*v.z + v.w*v.w;
  ss = wredsum(ss);
  __shared__ float red[4];
  if ((tid & 63) == 0) red[tid >> 6] = ss;
  __syncthreads();
  float tot = red[0] + red[1] + red[2] + red[3];
  float rs = rsqrtf(tot * (1.0f/1024.0f) + 1e-6f);
  const float* mrow = mod + (long)b * 3072;
  bf16* orow = out + (long)row * C_DS;
  #pragma unroll
  for (int j = 0; j < 4; ++j){
    int col = tid*4 + j;
    float val = ((&v.x)[j]) * rs * (1.0f + mrow[col]) + mrow[1024 + col];
    orow[col] = __float2bfloat16(val);
  }
}

// ---------------- RoPE + layout scatter ----------------
// qkv_p [b*800][2560] f32, qkv_s [b*48][2560] f32  (cols: q 0..2047 | k 2048..2303 | v 2304..2559)
// -> q_r bf16 [b][h][n][256], k_r bf16 [b][n][256], v_t bf16 [b][256][864] (transposed, zero-padded)
__global__ void rope_k(const float* __restrict__ qkv_p, const float* __restrict__ qkv_s,
                       bf16* __restrict__ q_r, bf16* __restrict__ k_r, bf16* __restrict__ v_t){
  int bn = blockIdx.x;
  int b = bn / C_N, n = bn - b * C_N;
  int d = threadIdx.x;  // 0..255
  const float* src = (n < C_SP) ? (qkv_p + ((long)b*C_SP + n) * 2560)
                                : (qkv_s + ((long)b*C_SS + (n - C_SP)) * 2560);
  int i = d & 127;
  float inv = expf(-(float)i * (9.210340371976184f / 128.0f)); // 1/10000^(i/128)
  float fr = (float)n * inv;
  float sn, cs;
  sincosf(fr, &sn, &cs);
  bool lo = d < 128;
  int dpair = lo ? d + 128 : d - 128;
  #pragma unroll
  for (int h = 0; h < C_H; ++h){
    float a = src[h*C_HD + d], o = src[h*C_HD + dpair];
    float r = lo ? (a*cs - o*sn) : (a*cs + o*sn);
    q_r[(((long)b*C_H + h)*C_N + n)*C_HD + d] = __float2bfloat16(r);
  }
  {
    float a = src[2048 + d], o = src[2048 + dpair];
    float r = lo ? (a*cs - o*sn) : (a*cs + o*sn);
    k_r[((long)b*C_N + n)*C_HD + d] = __float2bfloat16(r);
  }
  v_t[((long)b*C_HD + d)*C_NP + n] = __float2bfloat16(src[2304 + d]);
  if (n < C_NP - C_N)   // zero K-padding columns 848..863
    v_t[((long)b*C_HD + d)*C_NP + C_N + n] = __float2bfloat16(0.0f);
}

// ---------------- masked softmax over S rows (bf16 in/out, fp32 math) ----------------
__global__ void softmax_k(bf16* __restrict__ S){
  int m = blockIdx.x;        // 0..6783 (= h*848 + qn)
  int b = blockIdx.y;
  int qn = m % C_N;
  bf16* row = S + ((long)b * (C_H*C_N) + m) * C_NP;
  int tid = threadIdx.x, w = tid >> 6, lane = tid & 63;
  bool qpref = (qn < C_SP);
  float vals[4];
  float mx = -3.0e38f;
  #pragma unroll
  for (int j = 0; j < 4; ++j){
    int col = tid + j*256;
    float v = -3.0e38f;
    if (col < C_N && !(qpref && col >= C_SP)) v = __bfloat162float(row[col]);
    vals[j] = v; mx = fmaxf(mx, v);
  }
  mx = wredmax(mx);
  __shared__ float red[4];
  if (lane == 0) red[w] = mx;
  __syncthreads();
  mx = fmaxf(fmaxf(red[0], red[1]), fmaxf(red[2], red[3]));
  __syncthreads();
  float sum = 0.0f;
  #pragma unroll
  for (int j = 0; j < 4; ++j){
    float e = (vals[j] > -1.0e37f) ? __expf(vals[j] - mx) : 0.0f;
    vals[j] = e; sum += e;
  }
  sum = wredsum(sum);
  if (lane == 0) red[w] = sum;
  __syncthreads();
  sum = red[0] + red[1] + red[2] + red[3];
  float invs = 1.0f / sum;
  #pragma unroll
  for (int j = 0; j < 4; ++j){
    int col = tid + j*256;
    if (col < C_N) row[col] = __float2bfloat16(vals[j] * invs);
    else if (col < C_NP) row[col] = __float2bfloat16(0.0f);
  }
}

// ---------------- generic 128x128 bf16 MFMA GEMM: C_acc = A[M,K] @ W[N,K]^T ----------------
enum { M_F32 = 0, M_SBF16 = 1, M_ATTN_O = 2, M_RES_P = 3, M_RES_S = 4, M_OUT_P = 5, M_OUT_S = 6 };

template<int MODE>
__global__ __launch_bounds__(256, 2)
void gemm128(const bf16* __restrict__ Ab, long sA, int Ma,
             const bf16* __restrict__ Wb, long sW, int Nw,
             int K,
             void* __restrict__ Cb, long sC, int ldC, int Mc, int Nc,
             const float* __restrict__ aux0, long sAux0,
             const float* __restrict__ aux1,
             float scale)
{
  __shared__ bf16 As[128*32];
  __shared__ bf16 Bs[128*32];
  const int tid = threadIdx.x;
  const int w = tid >> 6, lane = tid & 63;
  const int wr = w >> 1, wc = w & 1;
  const int z = blockIdx.z;
  const int tm = blockIdx.x * 128, tn = blockIdx.y * 128;
  const bf16* A = Ab + (long)z * sA;
  const bf16* W = Wb + (long)z * sW;

  f32x4 acc[4][4] = {};

  // staging: chunk c = issue*256+tid; row=c>>2, colb=(c&3)*8; LDS offset = c*8 elems
  const int r0 = tid >> 2;
  const int cb = (tid & 3) * 8;
  int ar0 = tm + r0;       if (ar0 >= Ma) ar0 = Ma - 1;
  int ar1 = tm + r0 + 64;  if (ar1 >= Ma) ar1 = Ma - 1;
  int nr0 = tn + r0;       if (nr0 >= Nw) nr0 = Nw - 1;
  int nr1 = tn + r0 + 64;  if (nr1 >= Nw) nr1 = Nw - 1;
  const bf16* ga0 = A + (long)ar0 * K + cb;
  const bf16* ga1 = A + (long)ar1 * K + cb;
  const bf16* gw0 = W + (long)nr0 * K + cb;
  const bf16* gw1 = W + (long)nr1 * K + cb;
  bf16* lA0 = As + tid * 8;
  bf16* lA1 = As + (tid + 256) * 8;
  bf16* lB0 = Bs + tid * 8;
  bf16* lB1 = Bs + (tid + 256) * 8;

  const int a_off = (wr*64 + (lane & 15)) * 32 + (lane >> 4) * 8;
  const int b_off = (wc*64 + (lane & 15)) * 32 + (lane >> 4) * 8;

  for (int kt = 0; kt < K; kt += 32){
    GLD_LDS16(ga0, lA0); GLD_LDS16(ga1, lA1);
    GLD_LDS16(gw0, lB0); GLD_LDS16(gw1, lB1);
    ga0 += 32; ga1 += 32; gw0 += 32; gw1 += 32;
    __syncthreads();
    bf16x8 af[4], bfr[4];
    #pragma unroll
    for (int r = 0; r < 4; ++r) af[r]  = *(const bf16x8*)(As + a_off + r*512);
    #pragma unroll
    for (int c = 0; c < 4; ++c) bfr[c] = *(const bf16x8*)(Bs + b_off + c*512);
    #pragma unroll
    for (int r = 0; r < 4; ++r)
      #pragma unroll
      for (int c = 0; c < 4; ++c)
        acc[r][c] = MFMA16(af[r], bfr[c], acc[r][c]);
    __syncthreads();
  }

  // epilogue: C[row][col], col=lane&15, row=(lane>>4)*4+i within each 16x16 tile
  #pragma unroll
  for (int r = 0; r < 4; ++r){
    #pragma unroll
    for (int c = 0; c < 4; ++c){
      #pragma unroll
      for (int i = 0; i < 4; ++i){
        int row = tm + wr*64 + r*16 + (lane >> 4)*4 + i;
        int col = tn + wc*64 + c*16 + (lane & 15);
        if (row >= Mc || col >= Nc) continue;
        float v = acc[r][c][i];
        if constexpr (MODE == M_F32) {
          ((float*)Cb + (long)z*sC)[(long)row*ldC + col] = v;
        } else if constexpr (MODE == M_SBF16) {
          ((bf16*)Cb + (long)z*sC)[(long)row*ldC + col] = __float2bfloat16(v * scale);
        } else if constexpr (MODE == M_ATTN_O) {
          int h = row / C_N, qn = row - h*C_N;
          ((bf16*)Cb + (long)z*sC)[(long)qn*(C_H*C_HD) + h*C_HD + col] = __float2bfloat16(v);
        } else if constexpr (MODE == M_RES_P) {
          const float* X = aux0 + (long)z*sAux0;
          ((float*)Cb + (long)z*sC)[(long)row*ldC + col] = X[(long)row*ldC + col] + v;
        } else if constexpr (MODE == M_RES_S) {
          const float* X = aux0 + (long)z*sAux0;
          float g = aux1[z*3072 + 2048 + col];
          ((float*)Cb + (long)z*sC)[(long)row*ldC + col] = X[(long)row*ldC + col] + v * g;
        } else if constexpr (MODE == M_OUT_P) {
          ((float*)Cb)[(long)row*ldC + col] = aux0[(long)row*ldC + col] + v;
        } else if constexpr (MODE == M_OUT_S) {
          int bb = row / C_SS;
          ((float*)Cb)[(long)row*ldC + col] =
              aux0[(long)row*ldC + col] + v * aux1[bb*3072 + 2048 + col];
        }
      }
    }
  }
}

// ---------------- fused gate/up GEMM: act = gelu_tanh(A@Wg^T) * (A@Wu^T), bf16 out ----------------
// tile 128(M) x 64(N); M multiple of 128, N multiple of 64 (no masks needed)
__global__ __launch_bounds__(256, 2)
void gemm_gateup(const bf16* __restrict__ A, const bf16* __restrict__ Wg,
                 const bf16* __restrict__ Wu, int N, int K, bf16* __restrict__ act)
{
  __shared__ bf16 As[128*32];
  __shared__ bf16 Bg[64*32];
  __shared__ bf16 Bu[64*32];
  const int tid = threadIdx.x;
  const int w = tid >> 6, lane = tid & 63;
  const int wr = w >> 1, wc = w & 1;
  const long tm = (long)blockIdx.x * 128;
  const int tn = blockIdx.y * 64;

  f32x4 ag[4][2] = {}, au[4][2] = {};

  const int r0 = tid >> 2;
  const int cb = (tid & 3) * 8;
  const bf16* gA0 = A + (tm + r0) * K + cb;
  const bf16* gA1 = gA0 + (long)64 * K;
  const bf16* gG  = Wg + ((long)tn + r0) * K + cb;
  const bf16* gU  = Wu + ((long)tn + r0) * K + cb;
  bf16* lA0 = As + tid * 8;
  bf16* lA1 = As + (tid + 256) * 8;
  bf16* lG  = Bg + tid * 8;
  bf16* lU  = Bu + tid * 8;

  const int a_off = (wr*64 + (lane & 15)) * 32 + (lane >> 4) * 8;
  const int b_off = (wc*32 + (lane & 15)) * 32 + (lane >> 4) * 8;

  for (int kt = 0; kt < K; kt += 32){
    GLD_LDS16(gA0, lA0); GLD_LDS16(gA1, lA1);
    GLD_LDS16(gG, lG);   GLD_LDS16(gU, lU);
    gA0 += 32; gA1 += 32; gG += 32; gU += 32;
    __syncthreads();
    bf16x8 af[4], bg[2], bu[2];
    #pragma unroll
    for (int r = 0; r < 4; ++r) af[r] = *(const bf16x8*)(As + a_off + r*512);
    #pragma unroll
    for (int c = 0; c < 2; ++c){
      bg[c] = *(const bf16x8*)(Bg + b_off + c*512);
      bu[c] = *(const bf16x8*)(Bu + b_off + c*512);
    }
    #pragma unroll
    for (int r = 0; r < 4; ++r)
      #pragma unroll
      for (int c = 0; c < 2; ++c){
        ag[r][c] = MFMA16(af[r], bg[c], ag[r][c]);
        au[r][c] = MFMA16(af[r], bu[c], au[r][c]);
      }
    __syncthreads();
  }

  #pragma unroll
  for (int r = 0; r < 4; ++r)
    #pragma unroll
    for (int c = 0; c < 2; ++c)
      #pragma unroll
      for (int i = 0; i < 4; ++i){
        long row = tm + wr*64 + r*16 + (lane >> 4)*4 + i;
        int col = tn + wc*32 + c*16 + (lane & 15);
        float g = ag[r][c][i], u = au[r][c][i];
        float t = tanhf(0.7978845608f * (g + 0.044715f * g*g*g));
        act[row * N + col] = __float2bfloat16(0.5f * g * (1.0f + t) * u);
      }
}

// =====================================================================================
extern "C" void kernel_launch(void* const* d_in, const int* in_sizes, int n_in,
                              void* d_out, int out_size, void* d_ws, size_t ws_size,
                              hipStream_t stream)
{
  (void)in_sizes; (void)n_in; (void)out_size; (void)ws_size;
  const float* prefix_x    = (const float*)d_in[0];
  const float* suffix_x    = (const float*)d_in[1];
  const float* cond        = (const float*)d_in[2];
  const float* p_ln_w      = (const float*)d_in[3];
  const float* p_q_w       = (const float*)d_in[4];
  const float* p_k_w       = (const float*)d_in[5];
  const float* p_v_w       = (const float*)d_in[6];
  const float* p_o_w       = (const float*)d_in[7];
  const float* p_post_ln_w = (const float*)d_in[8];
  const float* p_gate_w    = (const float*)d_in[9];
  const float* p_up_w      = (const float*)d_in[10];
  const float* p_down_w    = (const float*)d_in[11];
  const float* s_ada1_w    = (const float*)d_in[12];
  const float* s_ada1_b    = (const float*)d_in[13];
  const float* s_q_w       = (const float*)d_in[14];
  const float* s_k_w       = (const float*)d_in[15];
  const float* s_v_w       = (const float*)d_in[16];
  const float* s_o_w       = (const float*)d_in[17];
  const float* s_ada2_w    = (const float*)d_in[18];
  const float* s_ada2_b    = (const float*)d_in[19];
  const float* s_gate_w    = (const float*)d_in[20];
  const float* s_up_w      = (const float*)d_in[21];
  const float* s_down_w    = (const float*)d_in[22];
  // d_in[23]=position_ids (arange, analytic), d_in[24]=attn_mask (structural, analytic)

  char* ws = (char*)d_ws;
  size_t off = 0;
  auto alloc = [&](size_t b){ size_t o = off; off += (b + 255) & ~(size_t)255; return o; };

  // persistent bf16 weights
  size_t oWqkv_p = alloc((size_t)2560*2048*2);
  size_t oWqkv_s = alloc((size_t)2560*1024*2);
  size_t oWo_p   = alloc((size_t)2048*2048*2);
  size_t oWo_s   = alloc((size_t)1024*2048*2);
  size_t oWg_p   = alloc((size_t)16384*2048*2);
  size_t oWu_p   = alloc((size_t)16384*2048*2);
  size_t oWd_p   = alloc((size_t)2048*16384*2);
  size_t oWg_s   = alloc((size_t)4096*1024*2);
  size_t oWu_s   = alloc((size_t)4096*1024*2);
  size_t oWd_s   = alloc((size_t)1024*4096*2);
  // persistent activations
  size_t oHp   = alloc((size_t)6400*2048*2);   // hp, later reused as hpost
  size_t oHs   = alloc((size_t)384*1024*2);    // hs, later reused as h2
  size_t oMod1 = alloc((size_t)8*3072*4);
  size_t oMod2 = alloc((size_t)8*3072*4);
  size_t oResS = alloc((size_t)384*1024*4);
  size_t oActS = alloc((size_t)384*4096*2);
  size_t oResP = alloc((size_t)6400*2048*4);
  // BIG region (attention-phase buffers; later overlaid by act_p)
  size_t oQkvP = alloc((size_t)6400*2560*4);
  size_t oQkvS = alloc((size_t)384*2560*4);
  size_t oQr   = alloc((size_t)8*8*848*256*2);
  size_t oKr   = alloc((size_t)8*848*256*2);
  size_t oVt   = alloc((size_t)8*256*864*2);
  size_t oS    = alloc((size_t)8*6784*864*2);
  size_t oO    = alloc((size_t)8*848*2048*2);
  size_t oActP = oQkvP;  // overlay: 6400*16384*2 = 209.7MB fits in 225.8MB region

  auto f2b = [&](const float* s, size_t dofs, long n){
    f2b_k<<<dim3((unsigned)((n/4 + 255)/256)), 256, 0, stream>>>(s, (bf16*)(ws + dofs), n);
  };
  // 1. convert weights -> bf16 (qkv concatenated)
  f2b(p_q_w, oWqkv_p,                        (long)2048*2048);
  f2b(p_k_w, oWqkv_p + (size_t)2048*2048*2,  (long)256*2048);
  f2b(p_v_w, oWqkv_p + (size_t)2304*2048*2,  (long)256*2048);
  f2b(s_q_w, oWqkv_s,                        (long)2048*1024);
  f2b(s_k_w, oWqkv_s + (size_t)2048*1024*2,  (long)256*1024);
  f2b(s_v_w, oWqkv_s + (size_t)2304*1024*2,  (long)256*1024);
  f2b(p_o_w, oWo_p,   (long)2048*2048);
  f2b(s_o_w, oWo_s,   (long)1024*2048);
  f2b(p_gate_w, oWg_p, (long)16384*2048);
  f2b(p_up_w,   oWu_p, (long)16384*2048);
  f2b(p_down_w, oWd_p, (long)2048*16384);
  f2b(s_gate_w, oWg_s, (long)4096*1024);
  f2b(s_up_w,   oWu_s, (long)4096*1024);
  f2b(s_down_w, oWd_s, (long)1024*4096);

  // 2. pre-norms
  gemma_norm_k<<<6400, 256, 0, stream>>>(prefix_x, p_ln_w, (bf16*)(ws + oHp));
  ada_mod_k<<<24, 256, 0, stream>>>(cond, s_ada1_w, s_ada1_b, s_ada2_w, s_ada2_b,
                                    (float*)(ws + oMod1), (float*)(ws + oMod2));
  ada_norm_k<<<384, 256, 0, stream>>>(suffix_x, (const float*)(ws + oMod1), (bf16*)(ws + oHs));

  // 3. qkv projections (fp32 out)
  gemm128<M_F32><<<dim3(50,20,1), 256, 0, stream>>>(
      (const bf16*)(ws+oHp), 0, 6400, (const bf16*)(ws+oWqkv_p), 0, 2560, 2048,
      ws+oQkvP, 0, 2560, 6400, 2560, nullptr, 0, nullptr, 1.0f);
  gemm128<M_F32><<<dim3(3,20,1), 256, 0, stream>>>(
      (const bf16*)(ws+oHs), 0, 384, (const bf16*)(ws+oWqkv_s), 0, 2560, 1024,
      ws+oQkvS, 0, 2560, 384, 2560, nullptr, 0, nullptr, 1.0f);

  // 4. RoPE + scatter to attention layouts
  rope_k<<<8*848, 256, 0, stream>>>((const float*)(ws+oQkvP), (const float*)(ws+oQkvS),
                                    (bf16*)(ws+oQr), (bf16*)(ws+oKr), (bf16*)(ws+oVt));

  // 5. S = QK^T * 1/16   (batched over b; M=6784=H*848, N=848->mask, K=256)
  gemm128<M_SBF16><<<dim3(53,7,8), 256, 0, stream>>>(
      (const bf16*)(ws+oQr), (long)6784*256, 6784,
      (const bf16*)(ws+oKr), (long)848*256, 848, 256,
      ws+oS, (long)6784*864, 864, 6784, 848, nullptr, 0, nullptr, 0.0625f);

  // 6. masked softmax (P in place, zero pad cols)
  softmax_k<<<dim3(6784,8), 256, 0, stream>>>((bf16*)(ws+oS));

  // 7. O = P @ V  (K=864 padded), scatter to [b][n][h*256+d]
  gemm128<M_ATTN_O><<<dim3(53,2,8), 256, 0, stream>>>(
      (const bf16*)(ws+oS), (long)6784*864, 6784,
      (const bf16*)(ws+oVt), (long)256*864, 256, 864,
      ws+oO, (long)848*2048, 2048, 6784, 256, nullptr, 0, nullptr, 1.0f);

  // 8. o-projections + residuals
  gemm128<M_RES_P><<<dim3(7,16,8), 256, 0, stream>>>(
      (const bf16*)(ws+oO), (long)848*2048, 800,
      (const bf16*)(ws+oWo_p), 0, 2048, 2048,
      ws+oResP, (long)800*2048, 2048, 800, 2048, prefix_x, (long)800*2048, nullptr, 1.0f);
  gemm128<M_RES_S><<<dim3(1,8,8), 256, 0, stream>>>(
      (const bf16*)(ws+oO) + (long)800*2048, (long)848*2048, 48,
      (const bf16*)(ws+oWo_s), 0, 1024, 2048,
      ws+oResS, (long)48*1024, 1024, 48, 1024, suffix_x, (long)48*1024,
      (const float*)(ws+oMod1), 1.0f);

  // 9. post-norms
  gemma_norm_k<<<6400, 256, 0, stream>>>((const float*)(ws+oResP), p_post_ln_w, (bf16*)(ws+oHp));
  ada_norm_k<<<384, 256, 0, stream>>>((const float*)(ws+oResS), (const float*)(ws+oMod2),
                                      (bf16*)(ws+oHs));

  // 10. MLPs
  gemm_gateup<<<dim3(50,256,1), 256, 0, stream>>>(
      (const bf16*)(ws+oHp), (const bf16*)(ws+oWg_p), (const bf16*)(ws+oWu_p),
      16384, 2048, (bf16*)(ws+oActP));
  gemm128<M_OUT_P><<<dim3(50,16,1), 256, 0, stream>>>(
      (const bf16*)(ws+oActP), 0, 6400, (const bf16*)(ws+oWd_p), 0, 2048, 16384,
      d_out, 0, 2048, 6400, 2048, (const float*)(ws+oResP), 0, nullptr, 1.0f);

  gemm_gateup<<<dim3(3,64,1), 256, 0, stream>>>(
      (const bf16*)(ws+oHs), (const bf16*)(ws+oWg_s), (const bf16*)(ws+oWu_s),
      4096, 1024, (bf16*)(ws+oActS));
  gemm128<M_OUT_S><<<dim3(3,8,1), 256, 0, stream>>>(
      (const bf16*)(ws+oActS), 0, 384, (const bf16*)(ws+oWd_s), 0, 1024, 4096,
      (float*)d_out + (size_t)6400*2048, 0, 1024, 384, 1024,
      (const float*)(ws+oResS), 0, (const float*)(ws+oMod2), 1.0f);
}

// Round 2
// 2835.167 us; speedup vs baseline: 1.2556x; 1.2556x over previous
//
#include <hip/hip_runtime.h>
#include <hip/hip_bf16.h>
#include <cmath>

using bf16 = __hip_bfloat16;
typedef short bf16x8 __attribute__((ext_vector_type(8)));
typedef float f32x4 __attribute__((ext_vector_type(4)));

#define GLD_LDS16(g, l) __builtin_amdgcn_global_load_lds( \
    (const __attribute__((address_space(1))) void*)(g),   \
    (__attribute__((address_space(3))) void*)(l), 16, 0, 0)

#define MFMA16(a,b,c) __builtin_amdgcn_mfma_f32_16x16x32_bf16((a),(b),(c),0,0,0)

// problem constants
#define C_SP 800
#define C_SS 48
#define C_B  8
#define C_N  848      // SP+SS
#define C_NP 864      // padded to 27*32
#define C_DP 2048
#define C_DS 1024
#define C_H  8
#define C_HD 256
#define C_FP 16384
#define C_FS 4096

__device__ inline float wredsum(float v){
  #pragma unroll
  for (int o = 32; o > 0; o >>= 1) v += __shfl_down(v, o, 64);
  return v;
}
__device__ inline float wredmax(float v){
  #pragma unroll
  for (int o = 32; o > 0; o >>= 1) v = fmaxf(v, __shfl_down(v, o, 64));
  return v;
}

// Two-level locality swizzle: region split by (lin&7) — round-robin XCD heuristic,
// each XCD works a contiguous slab of tile space so B-tiles land in ONE L2 —
// then GROUP_N=8 rasterization inside (concurrent blocks share 8 B-tiles + narrow A stripe).
__device__ inline void tile_swizzle(int lin, int nmt, int nnt, int& tm, int& tn){
  int total = nmt * nnt;
  int t;
  if ((total & 7) == 0) t = (lin & 7) * (total >> 3) + (lin >> 3);
  else t = lin;
  const int GN = 8;
  int band = GN * nmt;
  int g = t / band;
  int n0 = g * GN;
  int gw = nnt - n0; if (gw > GN) gw = GN;
  int r = t - g * band;
  tm = r / gw;
  tn = n0 + r % gw;
}

// ---------------- fused fp32 -> bf16 weight conversion (single launch) ----------------
struct ConvTab {
  const float* src[14];
  bf16* dst[14];
  int cum[15];   // cumulative block counts; each block = 2048 elements
};
__global__ void convert_all_k(ConvTab t){
  int b = blockIdx.x;
  int s = 0;
  #pragma unroll 1
  while (b >= t.cum[s+1]) ++s;
  long i = ((long)(b - t.cum[s]) * 256 + threadIdx.x) * 8;
  const float* src = t.src[s] + i;
  float4 v0 = *(const float4*)(src);
  float4 v1 = *(const float4*)(src + 4);
  bf16 o[8];
  o[0]=__float2bfloat16(v0.x); o[1]=__float2bfloat16(v0.y);
  o[2]=__float2bfloat16(v0.z); o[3]=__float2bfloat16(v0.w);
  o[4]=__float2bfloat16(v1.x); o[5]=__float2bfloat16(v1.y);
  o[6]=__float2bfloat16(v1.z); o[7]=__float2bfloat16(v1.w);
  *(int4*)(t.dst[s] + i) = *(const int4*)o;
}

// ---------------- gemma RMS norm (D=2048) -> bf16 ----------------
__global__ void gemma_norm_k(const float* __restrict__ x, const float* __restrict__ w,
                             bf16* __restrict__ out){
  int row = blockIdx.x;
  int tid = threadIdx.x;
  const float* xr = x + (long)row * C_DP;
  float4 v0 = *(const float4*)(xr + tid*4);
  float4 v1 = *(const float4*)(xr + 1024 + tid*4);
  float ss = v0.x*v0.x + v0.y*v0.y + v0.z*v0.z + v0.w*v0.w
           + v1.x*v1.x + v1.y*v1.y + v1.z*v1.z + v1.w*v1.w;
  ss = wredsum(ss);
  __shared__ float red[4];
  if ((tid & 63) == 0) red[tid >> 6] = ss;
  __syncthreads();
  float tot = red[0] + red[1] + red[2] + red[3];
  float rs = rsqrtf(tot * (1.0f/2048.0f) + 1e-6f);
  bf16* orow = out + (long)row * C_DP;
  const float* wv = w;
  #pragma unroll
  for (int j = 0; j < 4; ++j){
    int c0 = tid*4 + j;
    orow[c0]        = __float2bfloat16(((&v0.x)[j]) * rs * (1.0f + wv[c0]));
    orow[c0 + 1024] = __float2bfloat16(((&v1.x)[j]) * rs * (1.0f + wv[c0 + 1024]));
  }
}

// ---------------- ada modulation: mod = cond @ w^T + b (both layers) ----------------
__global__ void ada_mod_k(const float* __restrict__ cond,
                          const float* __restrict__ w1, const float* __restrict__ b1,
                          const float* __restrict__ w2, const float* __restrict__ b2,
                          float* __restrict__ mod1, float* __restrict__ mod2){
  int idx = blockIdx.x * 256 + threadIdx.x;   // 2*3072 outputs
  int sel = idx / 3072, col = idx - sel * 3072;
  const float* w = (sel ? w2 : w1) + (long)col * C_DS;
  float acc[8] = {0,0,0,0,0,0,0,0};
  for (int k = 0; k < C_DS; k += 4){
    float4 wv = *(const float4*)(w + k);
    #pragma unroll
    for (int b = 0; b < 8; ++b){
      float4 cv = *(const float4*)(cond + b*C_DS + k);
      acc[b] += wv.x*cv.x + wv.y*cv.y + wv.z*cv.z + wv.w*cv.w;
    }
  }
  float bias = (sel ? b2 : b1)[col];
  float* m = sel ? mod2 : mod1;
  #pragma unroll
  for (int b = 0; b < 8; ++b) m[b*3072 + col] = acc[b] + bias;
}

// ---------------- ada norm (D=1024): rms(x)*(1+scale)+shift -> bf16 ----------------
__global__ void ada_norm_k(const float* __restrict__ x, const float* __restrict__ mod,
                           bf16* __restrict__ out){
  int row = blockIdx.x;       // 0..383
  int b = row / C_SS;
  int tid = threadIdx.x;
  const float* xr = x + (long)row * C_DS;
  float4 v = *(const float4*)(xr + tid*4);
  float ss = v.x*v.x + v.y*v.y + v.z*v.z + v.w*v.w;
  ss = wredsum(ss);
  __shared__ float red[4];
  if ((tid & 63) == 0) red[tid >> 6] = ss;
  __syncthreads();
  float tot = red[0] + red[1] + red[2] + red[3];
  float rs = rsqrtf(tot * (1.0f/1024.0f) + 1e-6f);
  const float* mrow = mod + (long)b * 3072;
  bf16* orow = out + (long)row * C_DS;
  #pragma unroll
  for (int j = 0; j < 4; ++j){
    int col = tid*4 + j;
    float val = ((&v.x)[j]) * rs * (1.0f + mrow[col]) + mrow[1024 + col];
    orow[col] = __float2bfloat16(val);
  }
}

// ---------------- RoPE + layout scatter ----------------
__global__ void rope_k(const float* __restrict__ qkv_p, const float* __restrict__ qkv_s,
                       bf16* __restrict__ q_r, bf16* __restrict__ k_r, bf16* __restrict__ v_t){
  int bn = blockIdx.x;
  int b = bn / C_N, n = bn - b * C_N;
  int d = threadIdx.x;  // 0..255
  const float* src = (n < C_SP) ? (qkv_p + ((long)b*C_SP + n) * 2560)
                                : (qkv_s + ((long)b*C_SS + (n - C_SP)) * 2560);
  int i = d & 127;
  float inv = expf(-(float)i * (9.210340371976184f / 128.0f)); // 1/10000^(i/128)
  float fr = (float)n * inv;
  float sn, cs;
  sincosf(fr, &sn, &cs);
  bool lo = d < 128;
  int dpair = lo ? d + 128 : d - 128;
  #pragma unroll
  for (int h = 0; h < C_H; ++h){
    float a = src[h*C_HD + d], o = src[h*C_HD + dpair];
    float r = lo ? (a*cs - o*sn) : (a*cs + o*sn);
    q_r[(((long)b*C_H + h)*C_N + n)*C_HD + d] = __float2bfloat16(r);
  }
  {
    float a = src[2048 + d], o = src[2048 + dpair];
    float r = lo ? (a*cs - o*sn) : (a*cs + o*sn);
    k_r[((long)b*C_N + n)*C_HD + d] = __float2bfloat16(r);
  }
  v_t[((long)b*C_HD + d)*C_NP + n] = __float2bfloat16(src[2304 + d]);
  if (n < C_NP - C_N)   // zero K-padding columns 848..863
    v_t[((long)b*C_HD + d)*C_NP + C_N + n] = __float2bfloat16(0.0f);
}

// ---------------- masked softmax over S rows (bf16 in/out, fp32 math) ----------------
__global__ void softmax_k(bf16* __restrict__ S){
  int m = blockIdx.x;        // 0..6783 (= h*848 + qn)
  int b = blockIdx.y;
  int qn = m % C_N;
  bf16* row = S + ((long)b * (C_H*C_N) + m) * C_NP;
  int tid = threadIdx.x, w = tid >> 6, lane = tid & 63;
  bool qpref = (qn < C_SP);
  float vals[4];
  float mx = -3.0e38f;
  #pragma unroll
  for (int j = 0; j < 4; ++j){
    int col = tid + j*256;
    float v = -3.0e38f;
    if (col < C_N && !(qpref && col >= C_SP)) v = __bfloat162float(row[col]);
    vals[j] = v; mx = fmaxf(mx, v);
  }
  mx = wredmax(mx);
  __shared__ float red[4];
  if (lane == 0) red[w] = mx;
  __syncthreads();
  mx = fmaxf(fmaxf(red[0], red[1]), fmaxf(red[2], red[3]));
  __syncthreads();
  float sum = 0.0f;
  #pragma unroll
  for (int j = 0; j < 4; ++j){
    float e = (vals[j] > -1.0e37f) ? __expf(vals[j] - mx) : 0.0f;
    vals[j] = e; sum += e;
  }
  sum = wredsum(sum);
  if (lane == 0) red[w] = sum;
  __syncthreads();
  sum = red[0] + red[1] + red[2] + red[3];
  float invs = 1.0f / sum;
  #pragma unroll
  for (int j = 0; j < 4; ++j){
    int col = tid + j*256;
    if (col < C_N) row[col] = __float2bfloat16(vals[j] * invs);
    else if (col < C_NP) row[col] = __float2bfloat16(0.0f);
  }
}

// ---------------- generic 128x128 bf16 MFMA GEMM: C_acc = A[M,K] @ W[N,K]^T ----------------
enum { M_F32 = 0, M_SBF16 = 1, M_ATTN_O = 2, M_RES_P = 3, M_RES_S = 4, M_OUT_P = 5, M_OUT_S = 6 };

template<int MODE>
__global__ __launch_bounds__(256, 2)
void gemm128(int nmt, int nnt,
             const bf16* __restrict__ Ab, long sA, int Ma,
             const bf16* __restrict__ Wb, long sW, int Nw,
             int K,
             void* __restrict__ Cb, long sC, int ldC, int Mc, int Nc,
             const float* __restrict__ aux0, long sAux0,
             const float* __restrict__ aux1,
             float scale)
{
  __shared__ bf16 As[128*32];
  __shared__ bf16 Bs[128*32];
  const int tid = threadIdx.x;
  const int w = tid >> 6, lane = tid & 63;
  const int wr = w >> 1, wc = w & 1;
  const int z = blockIdx.z;
  int tmi, tni;
  tile_swizzle(blockIdx.x, nmt, nnt, tmi, tni);
  const int tm = tmi * 128, tn = tni * 128;
  const bf16* A = Ab + (long)z * sA;
  const bf16* W = Wb + (long)z * sW;

  f32x4 acc[4][4] = {};

  const int r0 = tid >> 2;
  const int cb = (tid & 3) * 8;
  int ar0 = tm + r0;       if (ar0 >= Ma) ar0 = Ma - 1;
  int ar1 = tm + r0 + 64;  if (ar1 >= Ma) ar1 = Ma - 1;
  int nr0 = tn + r0;       if (nr0 >= Nw) nr0 = Nw - 1;
  int nr1 = tn + r0 + 64;  if (nr1 >= Nw) nr1 = Nw - 1;
  const bf16* ga0 = A + (long)ar0 * K + cb;
  const bf16* ga1 = A + (long)ar1 * K + cb;
  const bf16* gw0 = W + (long)nr0 * K + cb;
  const bf16* gw1 = W + (long)nr1 * K + cb;
  bf16* lA0 = As + tid * 8;
  bf16* lA1 = As + (tid + 256) * 8;
  bf16* lB0 = Bs + tid * 8;
  bf16* lB1 = Bs + (tid + 256) * 8;

  const int a_off = (wr*64 + (lane & 15)) * 32 + (lane >> 4) * 8;
  const int b_off = (wc*64 + (lane & 15)) * 32 + (lane >> 4) * 8;

  for (int kt = 0; kt < K; kt += 32){
    GLD_LDS16(ga0, lA0); GLD_LDS16(ga1, lA1);
    GLD_LDS16(gw0, lB0); GLD_LDS16(gw1, lB1);
    ga0 += 32; ga1 += 32; gw0 += 32; gw1 += 32;
    __syncthreads();
    bf16x8 af[4], bfr[4];
    #pragma unroll
    for (int r = 0; r < 4; ++r) af[r]  = *(const bf16x8*)(As + a_off + r*512);
    #pragma unroll
    for (int c = 0; c < 4; ++c) bfr[c] = *(const bf16x8*)(Bs + b_off + c*512);
    #pragma unroll
    for (int r = 0; r < 4; ++r)
      #pragma unroll
      for (int c = 0; c < 4; ++c)
        acc[r][c] = MFMA16(af[r], bfr[c], acc[r][c]);
    __syncthreads();
  }

  #pragma unroll
  for (int r = 0; r < 4; ++r){
    #pragma unroll
    for (int c = 0; c < 4; ++c){
      #pragma unroll
      for (int i = 0; i < 4; ++i){
        int row = tm + wr*64 + r*16 + (lane >> 4)*4 + i;
        int col = tn + wc*64 + c*16 + (lane & 15);
        if (row >= Mc || col >= Nc) continue;
        float v = acc[r][c][i];
        if constexpr (MODE == M_F32) {
          ((float*)Cb + (long)z*sC)[(long)row*ldC + col] = v;
        } else if constexpr (MODE == M_SBF16) {
          ((bf16*)Cb + (long)z*sC)[(long)row*ldC + col] = __float2bfloat16(v * scale);
        } else if constexpr (MODE == M_ATTN_O) {
          int h = row / C_N, qn = row - h*C_N;
          ((bf16*)Cb + (long)z*sC)[(long)qn*(C_H*C_HD) + h*C_HD + col] = __float2bfloat16(v);
        } else if constexpr (MODE == M_RES_P) {
          const float* X = aux0 + (long)z*sAux0;
          ((float*)Cb + (long)z*sC)[(long)row*ldC + col] = X[(long)row*ldC + col] + v;
        } else if constexpr (MODE == M_RES_S) {
          const float* X = aux0 + (long)z*sAux0;
          float g = aux1[z*3072 + 2048 + col];
          ((float*)Cb + (long)z*sC)[(long)row*ldC + col] = X[(long)row*ldC + col] + v * g;
        } else if constexpr (MODE == M_OUT_P) {
          ((float*)Cb)[(long)row*ldC + col] = aux0[(long)row*ldC + col] + v;
        } else if constexpr (MODE == M_OUT_S) {
          int bb = row / C_SS;
          ((float*)Cb)[(long)row*ldC + col] =
              aux0[(long)row*ldC + col] + v * aux1[bb*3072 + 2048 + col];
        }
      }
    }
  }
}

// ---------------- fused gate/up GEMM: act = gelu_tanh(A@Wg^T) * (A@Wu^T), bf16 out ----------------
__global__ __launch_bounds__(256, 2)
void gemm_gateup(int nmt, int nnt,
                 const bf16* __restrict__ A, const bf16* __restrict__ Wg,
                 const bf16* __restrict__ Wu, int N, int K, bf16* __restrict__ act)
{
  __shared__ bf16 As[128*32];
  __shared__ bf16 Bg[64*32];
  __shared__ bf16 Bu[64*32];
  const int tid = threadIdx.x;
  const int w = tid >> 6, lane = tid & 63;
  const int wr = w >> 1, wc = w & 1;
  int tmi, tni;
  tile_swizzle(blockIdx.x, nmt, nnt, tmi, tni);
  const long tm = (long)tmi * 128;
  const int tn = tni * 64;

  f32x4 ag[4][2] = {}, au[4][2] = {};

  const int r0 = tid >> 2;
  const int cb = (tid & 3) * 8;
  const bf16* gA0 = A + (tm + r0) * K + cb;
  const bf16* gA1 = gA0 + (long)64 * K;
  const bf16* gG  = Wg + ((long)tn + r0) * K + cb;
  const bf16* gU  = Wu + ((long)tn + r0) * K + cb;
  bf16* lA0 = As + tid * 8;
  bf16* lA1 = As + (tid + 256) * 8;
  bf16* lG  = Bg + tid * 8;
  bf16* lU  = Bu + tid * 8;

  const int a_off = (wr*64 + (lane & 15)) * 32 + (lane >> 4) * 8;
  const int b_off = (wc*32 + (lane & 15)) * 32 + (lane >> 4) * 8;

  for (int kt = 0; kt < K; kt += 32){
    GLD_LDS16(gA0, lA0); GLD_LDS16(gA1, lA1);
    GLD_LDS16(gG, lG);   GLD_LDS16(gU, lU);
    gA0 += 32; gA1 += 32; gG += 32; gU += 32;
    __syncthreads();
    bf16x8 af[4], bg[2], bu[2];
    #pragma unroll
    for (int r = 0; r < 4; ++r) af[r] = *(const bf16x8*)(As + a_off + r*512);
    #pragma unroll
    for (int c = 0; c < 2; ++c){
      bg[c] = *(const bf16x8*)(Bg + b_off + c*512);
      bu[c] = *(const bf16x8*)(Bu + b_off + c*512);
    }
    #pragma unroll
    for (int r = 0; r < 4; ++r)
      #pragma unroll
      for (int c = 0; c < 2; ++c){
        ag[r][c] = MFMA16(af[r], bg[c], ag[r][c]);
        au[r][c] = MFMA16(af[r], bu[c], au[r][c]);
      }
    __syncthreads();
  }

  #pragma unroll
  for (int r = 0; r < 4; ++r)
    #pragma unroll
    for (int c = 0; c < 2; ++c)
      #pragma unroll
      for (int i = 0; i < 4; ++i){
        long row = tm + wr*64 + r*16 + (lane >> 4)*4 + i;
        int col = tn + wc*32 + c*16 + (lane & 15);
        float g = ag[r][c][i], u = au[r][c][i];
        float t = tanhf(0.7978845608f * (g + 0.044715f * g*g*g));
        act[row * N + col] = __float2bfloat16(0.5f * g * (1.0f + t) * u);
      }
}

// =====================================================================================
extern "C" void kernel_launch(void* const* d_in, const int* in_sizes, int n_in,
                              void* d_out, int out_size, void* d_ws, size_t ws_size,
                              hipStream_t stream)
{
  (void)in_sizes; (void)n_in; (void)out_size; (void)ws_size;
  const float* prefix_x    = (const float*)d_in[0];
  const float* suffix_x    = (const float*)d_in[1];
  const float* cond        = (const float*)d_in[2];
  const float* p_ln_w      = (const float*)d_in[3];
  const float* p_q_w       = (const float*)d_in[4];
  const float* p_k_w       = (const float*)d_in[5];
  const float* p_v_w       = (const float*)d_in[6];
  const float* p_o_w       = (const float*)d_in[7];
  const float* p_post_ln_w = (const float*)d_in[8];
  const float* p_gate_w    = (const float*)d_in[9];
  const float* p_up_w      = (const float*)d_in[10];
  const float* p_down_w    = (const float*)d_in[11];
  const float* s_ada1_w    = (const float*)d_in[12];
  const float* s_ada1_b    = (const float*)d_in[13];
  const float* s_q_w       = (const float*)d_in[14];
  const float* s_k_w       = (const float*)d_in[15];
  const float* s_v_w       = (const float*)d_in[16];
  const float* s_o_w       = (const float*)d_in[17];
  const float* s_ada2_w    = (const float*)d_in[18];
  const float* s_ada2_b    = (const float*)d_in[19];
  const float* s_gate_w    = (const float*)d_in[20];
  const float* s_up_w      = (const float*)d_in[21];
  const float* s_down_w    = (const float*)d_in[22];

  char* ws = (char*)d_ws;
  size_t off = 0;
  auto alloc = [&](size_t b){ size_t o = off; off += (b + 255) & ~(size_t)255; return o; };

  // persistent bf16 weights
  size_t oWqkv_p = alloc((size_t)2560*2048*2);
  size_t oWqkv_s = alloc((size_t)2560*1024*2);
  size_t oWo_p   = alloc((size_t)2048*2048*2);
  size_t oWo_s   = alloc((size_t)1024*2048*2);
  size_t oWg_p   = alloc((size_t)16384*2048*2);
  size_t oWu_p   = alloc((size_t)16384*2048*2);
  size_t oWd_p   = alloc((size_t)2048*16384*2);
  size_t oWg_s   = alloc((size_t)4096*1024*2);
  size_t oWu_s   = alloc((size_t)4096*1024*2);
  size_t oWd_s   = alloc((size_t)1024*4096*2);
  // persistent activations
  size_t oHp   = alloc((size_t)6400*2048*2);
  size_t oHs   = alloc((size_t)384*1024*2);
  size_t oMod1 = alloc((size_t)8*3072*4);
  size_t oMod2 = alloc((size_t)8*3072*4);
  size_t oResS = alloc((size_t)384*1024*4);
  size_t oActS = alloc((size_t)384*4096*2);
  size_t oResP = alloc((size_t)6400*2048*4);
  // BIG region (attention-phase buffers; later overlaid by act_p)
  size_t oQkvP = alloc((size_t)6400*2560*4);
  size_t oQkvS = alloc((size_t)384*2560*4);
  size_t oQr   = alloc((size_t)8*8*848*256*2);
  size_t oKr   = alloc((size_t)8*848*256*2);
  size_t oVt   = alloc((size_t)8*256*864*2);
  size_t oS    = alloc((size_t)8*6784*864*2);
  size_t oO    = alloc((size_t)8*848*2048*2);
  size_t oActP = oQkvP;  // overlay: 209.7MB fits in attention-phase region

  // 1. convert all weights -> bf16, single launch
  {
    ConvTab t;
    struct { const float* s; size_t d; long n; } segs[14] = {
      {p_q_w,    oWqkv_p,                       (long)2048*2048},
      {p_k_w,    oWqkv_p + (size_t)2048*2048*2, (long)256*2048},
      {p_v_w,    oWqkv_p + (size_t)2304*2048*2, (long)256*2048},
      {s_q_w,    oWqkv_s,                       (long)2048*1024},
      {s_k_w,    oWqkv_s + (size_t)2048*1024*2, (long)256*1024},
      {s_v_w,    oWqkv_s + (size_t)2304*1024*2, (long)256*1024},
      {p_o_w,    oWo_p,   (long)2048*2048},
      {s_o_w,    oWo_s,   (long)1024*2048},
      {p_gate_w, oWg_p,   (long)16384*2048},
      {p_up_w,   oWu_p,   (long)16384*2048},
      {p_down_w, oWd_p,   (long)2048*16384},
      {s_gate_w, oWg_s,   (long)4096*1024},
      {s_up_w,   oWu_s,   (long)4096*1024},
      {s_down_w, oWd_s,   (long)1024*4096},
    };
    int c = 0;
    for (int i = 0; i < 14; ++i){
      t.src[i] = segs[i].s;
      t.dst[i] = (bf16*)(ws + segs[i].d);
      t.cum[i] = c;
      c += (int)(segs[i].n / 2048);
    }
    t.cum[14] = c;
    convert_all_k<<<c, 256, 0, stream>>>(t);
  }

  // 2. pre-norms
  gemma_norm_k<<<6400, 256, 0, stream>>>(prefix_x, p_ln_w, (bf16*)(ws + oHp));
  ada_mod_k<<<24, 256, 0, stream>>>(cond, s_ada1_w, s_ada1_b, s_ada2_w, s_ada2_b,
                                    (float*)(ws + oMod1), (float*)(ws + oMod2));
  ada_norm_k<<<384, 256, 0, stream>>>(suffix_x, (const float*)(ws + oMod1), (bf16*)(ws + oHs));

  // 3. qkv projections (fp32 out)
  gemm128<M_F32><<<dim3(50*20,1,1), 256, 0, stream>>>(50, 20,
      (const bf16*)(ws+oHp), 0, 6400, (const bf16*)(ws+oWqkv_p), 0, 2560, 2048,
      ws+oQkvP, 0, 2560, 6400, 2560, nullptr, 0, nullptr, 1.0f);
  gemm128<M_F32><<<dim3(3*20,1,1), 256, 0, stream>>>(3, 20,
      (const bf16*)(ws+oHs), 0, 384, (const bf16*)(ws+oWqkv_s), 0, 2560, 1024,
      ws+oQkvS, 0, 2560, 384, 2560, nullptr, 0, nullptr, 1.0f);

  // 4. RoPE + scatter
  rope_k<<<8*848, 256, 0, stream>>>((const float*)(ws+oQkvP), (const float*)(ws+oQkvS),
                                    (bf16*)(ws+oQr), (bf16*)(ws+oKr), (bf16*)(ws+oVt));

  // 5. S = QK^T * 1/16
  gemm128<M_SBF16><<<dim3(53*7,1,8), 256, 0, stream>>>(53, 7,
      (const bf16*)(ws+oQr), (long)6784*256, 6784,
      (const bf16*)(ws+oKr), (long)848*256, 848, 256,
      ws+oS, (long)6784*864, 864, 6784, 848, nullptr, 0, nullptr, 0.0625f);

  // 6. masked softmax
  softmax_k<<<dim3(6784,8), 256, 0, stream>>>((bf16*)(ws+oS));

  // 7. O = P @ V
  gemm128<M_ATTN_O><<<dim3(53*2,1,8), 256, 0, stream>>>(53, 2,
      (const bf16*)(ws+oS), (long)6784*864, 6784,
      (const bf16*)(ws+oVt), (long)256*864, 256, 864,
      ws+oO, (long)848*2048, 2048, 6784, 256, nullptr, 0, nullptr, 1.0f);

  // 8. o-projections + residuals
  gemm128<M_RES_P><<<dim3(7*16,1,8), 256, 0, stream>>>(7, 16,
      (const bf16*)(ws+oO), (long)848*2048, 800,
      (const bf16*)(ws+oWo_p), 0, 2048, 2048,
      ws+oResP, (long)800*2048, 2048, 800, 2048, prefix_x, (long)800*2048, nullptr, 1.0f);
  gemm128<M_RES_S><<<dim3(1*8,1,8), 256, 0, stream>>>(1, 8,
      (const bf16*)(ws+oO) + (long)800*2048, (long)848*2048, 48,
      (const bf16*)(ws+oWo_s), 0, 1024, 2048,
      ws+oResS, (long)48*1024, 1024, 48, 1024, suffix_x, (long)48*1024,
      (const float*)(ws+oMod1), 1.0f);

  // 9. post-norms
  gemma_norm_k<<<6400, 256, 0, stream>>>((const float*)(ws+oResP), p_post_ln_w, (bf16*)(ws+oHp));
  ada_norm_k<<<384, 256, 0, stream>>>((const float*)(ws+oResS), (const float*)(ws+oMod2),
                                      (bf16*)(ws+oHs));

  // 10. MLPs
  gemm_gateup<<<dim3(50*256,1,1), 256, 0, stream>>>(50, 256,
      (const bf16*)(ws+oHp), (const bf16*)(ws+oWg_p), (const bf16*)(ws+oWu_p),
      16384, 2048, (bf16*)(ws+oActP));
  gemm128<M_OUT_P><<<dim3(50*16,1,1), 256, 0, stream>>>(50, 16,
      (const bf16*)(ws+oActP), 0, 6400, (const bf16*)(ws+oWd_p), 0, 2048, 16384,
      d_out, 0, 2048, 6400, 2048, (const float*)(ws+oResP), 0, nullptr, 1.0f);

  gemm_gateup<<<dim3(3*64,1,1), 256, 0, stream>>>(3, 64,
      (const bf16*)(ws+oHs), (const bf16*)(ws+oWg_s), (const bf16*)(ws+oWu_s),
      4096, 1024, (bf16*)(ws+oActS));
  gemm128<M_OUT_S><<<dim3(3*8,1,1), 256, 0, stream>>>(3, 8,
      (const bf16*)(ws+oActS), 0, 384, (const bf16*)(ws+oWd_s), 0, 1024, 4096,
      (float*)d_out + (size_t)6400*2048, 0, 1024, 384, 1024,
      (const float*)(ws+oResS), 0, (const float*)(ws+oMod2), 1.0f);
}